// Round 17
// baseline (338.272 us; speedup 1.0000x reference)
//
#include <hip/hip_runtime.h>
#include <math.h>

#define H 128
#define RBITS 14
#define RSIZE 16384       // nodes per range (64 KB packed LDS histogram, 4 passes over E)
#define NCHUNK 96         // edge chunks

typedef __attribute__((ext_vector_type(8))) short bf16x8;
typedef __attribute__((ext_vector_type(4))) float f32x4;

__device__ inline unsigned short f2bf(float f) {      // RNE float->bf16
  unsigned u = __float_as_uint(f);
  return (unsigned short)((u + 0x7FFF + ((u >> 16) & 1)) >> 16);
}

// ---------------- weight split: fp32 W[Kx128] -> hi/lo bf16 in B-frag order, once per launch ----------------
struct WSplitArgs {
  const float* W[5];
  int K[5];
  int off[6];     // in shorts, cumulative frag-space offsets
};
__global__ __launch_bounds__(256) void k_wsplit(WSplitArgs a, short* __restrict__ hi_buf,
                                                short* __restrict__ lo_buf) {
  int idx = blockIdx.x * 256 + threadIdx.x;
  if (idx >= a.off[5]) return;
  int wsel = 0;
  while (idx >= a.off[wsel + 1]) ++wsel;
  int lidx = idx - a.off[wsel];
  int j  = lidx & 7;
  int ln = (lidx >> 3) & 63;
  int ct = (lidx >> 9) & 7;
  int kt = lidx >> 12;
  int k = (kt << 5) | ((ln >> 4) << 3) | j;
  int n = (ct << 4) | (ln & 15);
  float v = (k < a.K[wsel]) ? a.W[wsel][(size_t)k * H + n] : 0.f;
  unsigned short hi = f2bf(v);
  float hif = __uint_as_float((unsigned)hi << 16);
  unsigned short lo = f2bf(v - hif);
  hi_buf[idx] = (short)hi;
  lo_buf[idx] = (short)lo;
}

// ---------------- split-bf16 MFMA GEMM body (A fp32 from global) ----------------
__device__ __forceinline__ void gemm_body(int blk, int tid,
                                          const float* __restrict__ A,
                                          const short* __restrict__ whi,
                                          const short* __restrict__ wlo,
                                          const float* __restrict__ bias,
                                          float* __restrict__ out_f,
                                          unsigned short* __restrict__ out_bf,
                                          int N, int K, int do_silu) {
  const int w = tid >> 6;
  const int l = tid & 63;
  const int q = l >> 4;
  const int m = l & 15;
  const int rbase = blk * 64 + w * 16;
  const int row = rbase + m;
  const bool rowOK = row < N;
  const float* Ap = A + (size_t)(rowOK ? row : 0) * K;
  const int KT = (K + 31) >> 5;

  f32x4 acc[8];
#pragma unroll
  for (int ct = 0; ct < 8; ++ct) acc[ct] = (f32x4){0.f, 0.f, 0.f, 0.f};

  for (int kt = 0; kt < KT; ++kt) {
    int kbase = kt * 32 + q * 8;
    float f[8];
    if (rowOK && kbase + 8 <= K) {
      float4 f0 = *(const float4*)(Ap + kbase);
      float4 f1 = *(const float4*)(Ap + kbase + 4);
      f[0] = f0.x; f[1] = f0.y; f[2] = f0.z; f[3] = f0.w;
      f[4] = f1.x; f[5] = f1.y; f[6] = f1.z; f[7] = f1.w;
    } else {
#pragma unroll
      for (int j = 0; j < 8; ++j)
        f[j] = (rowOK && kbase + j < K) ? Ap[kbase + j] : 0.f;
    }
    union { bf16x8 v; short s[8]; } ah, al;
#pragma unroll
    for (int j = 0; j < 8; ++j) {
      unsigned short hi = f2bf(f[j]);
      ah.s[j] = (short)hi;
      float hif = __uint_as_float((unsigned)hi << 16);
      al.s[j] = (short)f2bf(f[j] - hif);
    }
    const short* bh_base = whi + ((size_t)(kt * 8) * 64 + l) * 8;
    const short* bl_base = wlo + ((size_t)(kt * 8) * 64 + l) * 8;
#pragma unroll
    for (int ct = 0; ct < 8; ++ct) {
      bf16x8 bh = *(const bf16x8*)(bh_base + (size_t)ct * 512);
      bf16x8 bl = *(const bf16x8*)(bl_base + (size_t)ct * 512);
      acc[ct] = __builtin_amdgcn_mfma_f32_16x16x32_bf16(ah.v, bh, acc[ct], 0, 0, 0);
      acc[ct] = __builtin_amdgcn_mfma_f32_16x16x32_bf16(al.v, bh, acc[ct], 0, 0, 0);
      acc[ct] = __builtin_amdgcn_mfma_f32_16x16x32_bf16(ah.v, bl, acc[ct], 0, 0, 0);
    }
  }

  int orow[4]; bool ok[4];
#pragma unroll
  for (int r = 0; r < 4; ++r) { orow[r] = rbase + q * 4 + r; ok[r] = orow[r] < N; }
#pragma unroll
  for (int ct = 0; ct < 8; ++ct) {
    int col = ct * 16 + m;
    float bcol = bias[col];
    if (out_bf) {
#pragma unroll
      for (int r = 0; r < 4; ++r) {
        if (ok[r]) {
          float v = acc[ct][r] + bcol;
          v = v / (1.f + expf(-v));     // silu
          out_bf[(size_t)orow[r] * H + col] = f2bf(v);
        }
      }
    } else {
#pragma unroll
      for (int r = 0; r < 4; ++r) {
        if (ok[r]) {
          float v = acc[ct][r] + bcol;
          if (do_silu) v = v / (1.f + expf(-v));
          out_f[(size_t)orow[r] * H + col] = v;
        }
      }
    }
  }
}

// ---------------- bf16-A MFMA GEMM: A[N x 128] bf16 rows; acc = A*Wh + A*Wl (2-term) ----------------
__global__ __launch_bounds__(256) void k_gemm_bfA(const unsigned short* __restrict__ A,
                                                  const short* __restrict__ whi,
                                                  const short* __restrict__ wlo,
                                                  const float* __restrict__ bias,
                                                  const float* __restrict__ onorm, // fold into bf16 out
                                                  float* __restrict__ out_f,
                                                  unsigned short* __restrict__ out_bf,
                                                  int N, int do_silu) {
  const int t = threadIdx.x;
  const int w = t >> 6, l = t & 63, q = l >> 4, m = l & 15;
  const int rbase = blockIdx.x * 64 + w * 16;
  const int row = rbase + m;
  const bool rowOK = row < N;
  const short* Ap = (const short*)(A + (size_t)(rowOK ? row : 0) * H);

  f32x4 acc[8];
#pragma unroll
  for (int ct = 0; ct < 8; ++ct) acc[ct] = (f32x4){0.f, 0.f, 0.f, 0.f};

#pragma unroll
  for (int kt = 0; kt < 4; ++kt) {
    bf16x8 ah;
    if (rowOK) ah = *(const bf16x8*)(Ap + kt * 32 + q * 8);
    else       ah = (bf16x8){0,0,0,0,0,0,0,0};
    const short* bh_base = whi + ((size_t)(kt * 8) * 64 + l) * 8;
    const short* bl_base = wlo + ((size_t)(kt * 8) * 64 + l) * 8;
#pragma unroll
    for (int ct = 0; ct < 8; ++ct) {
      bf16x8 bh = *(const bf16x8*)(bh_base + (size_t)ct * 512);
      bf16x8 bl = *(const bf16x8*)(bl_base + (size_t)ct * 512);
      acc[ct] = __builtin_amdgcn_mfma_f32_16x16x32_bf16(ah, bh, acc[ct], 0, 0, 0);
      acc[ct] = __builtin_amdgcn_mfma_f32_16x16x32_bf16(ah, bl, acc[ct], 0, 0, 0);
    }
  }

  int orow[4]; bool ok[4]; float on_[4];
#pragma unroll
  for (int r = 0; r < 4; ++r) {
    orow[r] = rbase + q * 4 + r;
    ok[r] = orow[r] < N;
    on_[r] = (out_bf && onorm && ok[r]) ? onorm[orow[r]] : 1.f;
  }
#pragma unroll
  for (int ct = 0; ct < 8; ++ct) {
    int col = ct * 16 + m;
    float bcol = bias[col];
    if (out_bf) {
#pragma unroll
      for (int r = 0; r < 4; ++r) {
        if (ok[r]) {
          float v = acc[ct][r] + bcol;
          v = v / (1.f + expf(-v));     // silu
          out_bf[(size_t)orow[r] * H + col] = f2bf(v * on_[r]);
        }
      }
    } else {
#pragma unroll
      for (int r = 0; r < 4; ++r) {
        if (ok[r]) {
          float v = acc[ct][r] + bcol;
          if (do_silu) v = v / (1.f + expf(-v));
          out_f[(size_t)orow[r] * H + col] = v;
        }
      }
    }
  }
}

// ---------------- front: [zero pooled+gcount] || [embedding_in GEMM] || [hist] in ONE launch ----------------
__global__ __launch_bounds__(256) void k_front(const int* __restrict__ src,
                                               const int* __restrict__ dst,
                                               int* __restrict__ ppack, int E,
                                               const float* __restrict__ x,
                                               const short* __restrict__ whi_in,
                                               const short* __restrict__ wlo_in,
                                               const float* __restrict__ b_in,
                                               unsigned short* __restrict__ hb0,
                                               float* __restrict__ pooled, int GH,
                                               int* __restrict__ gcount,
                                               int N, int K_IN, int zb, int gblk) {
  __shared__ int h[RSIZE];
  int b = blockIdx.x;
  int t = threadIdx.x;
  if (b < zb) {
    int idx = b * 256 + t;
    if (idx < GH) pooled[idx] = 0.f;
    if (b == 0 && t == 0) *gcount = 0;
    return;
  }
  b -= zb;
  if (b < gblk) {
    // embedding_in: hb0 = bf16(silu(x @ W_in + b_in))  (onorm applied in gather-0)
    gemm_body(b, t, x, whi_in, wlo_in, b_in, nullptr, hb0, N, K_IN, 1);
    return;
  }
  b -= gblk;
  int r = b / NCHUNK, c = b % NCHUNK;
  int base = r << RBITS;
  for (int i = t; i < RSIZE; i += 256) h[i] = 0;
  __syncthreads();
  int e0 = (int)(((long long)E * c) / NCHUNK);
  int e1 = (int)(((long long)E * (c + 1)) / NCHUNK);
  for (int e = e0 + t; e < e1; e += 256) {
    unsigned ls = (unsigned)(src[e] - base);
    if (ls < RSIZE) atomicAdd(&h[ls], 1);
    unsigned ld = (unsigned)(dst[e] - base);
    if (ld < RSIZE) atomicAdd(&h[ld], 0x10000);
  }
  __syncthreads();
  int* p = ppack + (((size_t)(r * NCHUNK + c)) << RBITS);
  for (int i = t; i < RSIZE; i += 256) p[i] = h[i];
}

// ---------------- mid: degrees/norms + ppack chunk-prefix + block-atomic row_start ----------------
__global__ __launch_bounds__(1024) void k_mid(int* __restrict__ ppack,
                                              int* __restrict__ deg,
                                              float* __restrict__ onorm,
                                              float* __restrict__ inorm,
                                              int* __restrict__ row_start,
                                              int* __restrict__ gcount, int N) {
  __shared__ int buf[1024];
  __shared__ int base_s;
  int i = blockIdx.x * 1024 + threadIdx.x;
  int run = 0;
  if (i < N) {
    int r = i >> RBITS, l = i & (RSIZE - 1);
    size_t rb = ((size_t)r * NCHUNK) << RBITS;
    int sumS = 0;
    for (int c = 0; c < NCHUNK; ++c) {
      size_t idx = rb + ((size_t)c << RBITS) + l;
      int v = ppack[idx];
      sumS += v & 0xFFFF;
      ppack[idx] = run;
      run += (v >> 16) & 0xFFFF;
    }
    deg[i] = run;
    int od = sumS < 1 ? 1 : sumS;
    int id = run < 1 ? 1 : run;
    onorm[i] = rsqrtf((float)od);
    inorm[i] = rsqrtf((float)id);
  }
  buf[threadIdx.x] = run;
  __syncthreads();
#pragma unroll
  for (int off = 1; off < 1024; off <<= 1) {
    int tv = 0;
    if (threadIdx.x >= off) tv = buf[threadIdx.x - off];
    __syncthreads();
    if (threadIdx.x >= off) buf[threadIdx.x] += tv;
    __syncthreads();
  }
  if (threadIdx.x == 1023) base_s = atomicAdd(gcount, buf[1023]);
  __syncthreads();
  if (i < N) row_start[i] = base_s + buf[threadIdx.x] - run;
}

// ---------------- CSR fill: LDS cursors seeded from row_start + chunk prefix ----------------
__global__ __launch_bounds__(256) void k_fill_nr(const int* __restrict__ src,
                                                 const int* __restrict__ dst,
                                                 const int* __restrict__ row_start,
                                                 const int* __restrict__ ppfx,
                                                 int* __restrict__ csr, int N, int E) {
  int r = blockIdx.x / NCHUNK, c = blockIdx.x % NCHUNK;
  int base = r << RBITS;
  __shared__ int cur[RSIZE];
  const int* pd = ppfx + (((size_t)(r * NCHUNK + c)) << RBITS);
  for (int i = threadIdx.x; i < RSIZE; i += 256) {
    int node = base + i;
    cur[i] = (node < N) ? (row_start[node] + pd[i]) : 0;
  }
  __syncthreads();
  int e0 = (int)(((long long)E * c) / NCHUNK);
  int e1 = (int)(((long long)E * (c + 1)) / NCHUNK);
  for (int e = e0 + threadIdx.x; e < e1; e += 256) {
    unsigned ld = (unsigned)(dst[e] - base);
    if (ld < RSIZE) {
      int pos = atomicAdd(&cur[ld], 1);   // LDS atomic
      csr[pos] = src[e];
    }
  }
}

// ---------------- gather (R14 form): edge-paired + unroll x2, 4 edges/iter, 2 loads in flight ----------------
__global__ __launch_bounds__(64) void k_gather_bf(const unsigned* __restrict__ hb, // N x 64 words
                                                  const int* __restrict__ csr_src,
                                                  const int* __restrict__ row_start,
                                                  const int* __restrict__ deg,
                                                  const float* __restrict__ onorm, // null if pre-folded
                                                  const float* __restrict__ inorm,
                                                  unsigned* __restrict__ aggb, int N) {
  int v = blockIdx.x;
  int t = threadIdx.x;
  int half = t >> 5, u = t & 31;
  int b = row_start[v], e = b + deg[v];
  float a0 = 0.f, a1 = 0.f, a2 = 0.f, a3 = 0.f;
  int i = b;
  if (onorm) {
    for (; i + 4 <= e; i += 4) {          // two independent pairs -> 2 loads in flight
      int s0 = csr_src[i + half];
      int s1 = csr_src[i + 2 + half];
      float on0 = onorm[s0], on1 = onorm[s1];
      uint2 p0 = *(const uint2*)(hb + (size_t)s0 * 64 + 2 * u);
      uint2 p1 = *(const uint2*)(hb + (size_t)s1 * 64 + 2 * u);
      a0 += __uint_as_float(p0.x << 16) * on0;
      a1 += __uint_as_float(p0.x & 0xFFFF0000u) * on0;
      a2 += __uint_as_float(p0.y << 16) * on0;
      a3 += __uint_as_float(p0.y & 0xFFFF0000u) * on0;
      a0 += __uint_as_float(p1.x << 16) * on1;
      a1 += __uint_as_float(p1.x & 0xFFFF0000u) * on1;
      a2 += __uint_as_float(p1.y << 16) * on1;
      a3 += __uint_as_float(p1.y & 0xFFFF0000u) * on1;
    }
    for (; i + 2 <= e; i += 2) {
      int s = csr_src[i + half];
      float on = onorm[s];
      uint2 p = *(const uint2*)(hb + (size_t)s * 64 + 2 * u);
      a0 += __uint_as_float(p.x << 16) * on;
      a1 += __uint_as_float(p.x & 0xFFFF0000u) * on;
      a2 += __uint_as_float(p.y << 16) * on;
      a3 += __uint_as_float(p.y & 0xFFFF0000u) * on;
    }
    if (i < e && half == 0) {
      int s = csr_src[i];
      float on = onorm[s];
      uint2 p = *(const uint2*)(hb + (size_t)s * 64 + 2 * u);
      a0 += __uint_as_float(p.x << 16) * on;
      a1 += __uint_as_float(p.x & 0xFFFF0000u) * on;
      a2 += __uint_as_float(p.y << 16) * on;
      a3 += __uint_as_float(p.y & 0xFFFF0000u) * on;
    }
  } else {
    for (; i + 4 <= e; i += 4) {
      int s0 = csr_src[i + half];
      int s1 = csr_src[i + 2 + half];
      uint2 p0 = *(const uint2*)(hb + (size_t)s0 * 64 + 2 * u);
      uint2 p1 = *(const uint2*)(hb + (size_t)s1 * 64 + 2 * u);
      a0 += __uint_as_float(p0.x << 16);
      a1 += __uint_as_float(p0.x & 0xFFFF0000u);
      a2 += __uint_as_float(p0.y << 16);
      a3 += __uint_as_float(p0.y & 0xFFFF0000u);
      a0 += __uint_as_float(p1.x << 16);
      a1 += __uint_as_float(p1.x & 0xFFFF0000u);
      a2 += __uint_as_float(p1.y << 16);
      a3 += __uint_as_float(p1.y & 0xFFFF0000u);
    }
    for (; i + 2 <= e; i += 2) {
      int s = csr_src[i + half];
      uint2 p = *(const uint2*)(hb + (size_t)s * 64 + 2 * u);
      a0 += __uint_as_float(p.x << 16);
      a1 += __uint_as_float(p.x & 0xFFFF0000u);
      a2 += __uint_as_float(p.y << 16);
      a3 += __uint_as_float(p.y & 0xFFFF0000u);
    }
    if (i < e && half == 0) {
      int s = csr_src[i];
      uint2 p = *(const uint2*)(hb + (size_t)s * 64 + 2 * u);
      a0 += __uint_as_float(p.x << 16);
      a1 += __uint_as_float(p.x & 0xFFFF0000u);
      a2 += __uint_as_float(p.y << 16);
      a3 += __uint_as_float(p.y & 0xFFFF0000u);
    }
  }
  // combine halves (xor-32 swap) — adds even-edge and odd-edge partial sums
  a0 += __shfl_xor(a0, 32, 64);
  a1 += __shfl_xor(a1, 32, 64);
  a2 += __shfl_xor(a2, 32, 64);
  a3 += __shfl_xor(a3, 32, 64);
  if (half == 0) {
    float inn = inorm[v];
    uint2 o;
    o.x = (unsigned)f2bf(a0 * inn) | ((unsigned)f2bf(a1 * inn) << 16);
    o.y = (unsigned)f2bf(a2 * inn) | ((unsigned)f2bf(a3 * inn) << 16);
    *(uint2*)(aggb + (size_t)v * 64 + 2 * u) = o;
  }
}

// ---------------- fused tail: h3 = silu(Abf@Wg2+b2); hf = h3@Wout+bo; pooled += segsum(hf) ----------------
__global__ __launch_bounds__(256) void k_final(const unsigned short* __restrict__ A, // bf16 rows
                                               const short* __restrict__ whi2,
                                               const short* __restrict__ wlo2,
                                               const float* __restrict__ b2,
                                               const short* __restrict__ whio,
                                               const short* __restrict__ wloo,
                                               const float* __restrict__ bo,
                                               const int* __restrict__ gid,
                                               float* __restrict__ pooled, int N) {
  __shared__ float As[64][132];
  const int t = threadIdx.x;
  const int w = t >> 6, l = t & 63, q = l >> 4, m = l & 15;
  const int blk0 = blockIdx.x * 64;
  const int rbase = blk0 + w * 16;
  const int row = rbase + m;
  const bool rowOK = row < N;
  const short* Ap = (const short*)(A + (size_t)(rowOK ? row : 0) * H);

  f32x4 acc[8];
#pragma unroll
  for (int ct = 0; ct < 8; ++ct) acc[ct] = (f32x4){0.f, 0.f, 0.f, 0.f};

  // ---- GEMM 1: silu(Abf @ Wg2 + b2), 2-term ----
#pragma unroll
  for (int kt = 0; kt < 4; ++kt) {
    bf16x8 ah;
    if (rowOK) ah = *(const bf16x8*)(Ap + kt * 32 + q * 8);
    else       ah = (bf16x8){0,0,0,0,0,0,0,0};
    const short* bh_base = whi2 + ((size_t)(kt * 8) * 64 + l) * 8;
    const short* bl_base = wlo2 + ((size_t)(kt * 8) * 64 + l) * 8;
#pragma unroll
    for (int ct = 0; ct < 8; ++ct) {
      bf16x8 bh = *(const bf16x8*)(bh_base + (size_t)ct * 512);
      bf16x8 bl = *(const bf16x8*)(bl_base + (size_t)ct * 512);
      acc[ct] = __builtin_amdgcn_mfma_f32_16x16x32_bf16(ah, bh, acc[ct], 0, 0, 0);
      acc[ct] = __builtin_amdgcn_mfma_f32_16x16x32_bf16(ah, bl, acc[ct], 0, 0, 0);
    }
  }
#pragma unroll
  for (int ct = 0; ct < 8; ++ct) {
    int col = ct * 16 + m;
    float bcol = b2[col];
#pragma unroll
    for (int r = 0; r < 4; ++r) {
      float v = acc[ct][r] + bcol;
      v = v / (1.f + expf(-v));         // silu
      As[w * 16 + q * 4 + r][col] = v;
    }
  }
  __syncthreads();

  // ---- GEMM 2: (h3 fp32 from LDS) @ Wout + bo, 3-term ----
#pragma unroll
  for (int ct = 0; ct < 8; ++ct) acc[ct] = (f32x4){0.f, 0.f, 0.f, 0.f};
#pragma unroll
  for (int kt = 0; kt < 4; ++kt) {
    int kbase = kt * 32 + q * 8;
    float f[8];
    *(float4*)&f[0] = *(const float4*)(&As[w * 16 + m][kbase]);
    *(float4*)&f[4] = *(const float4*)(&As[w * 16 + m][kbase + 4]);
    union { bf16x8 v; short s[8]; } ah, al;
#pragma unroll
    for (int j = 0; j < 8; ++j) {
      unsigned short hi = f2bf(f[j]);
      ah.s[j] = (short)hi;
      float hif = __uint_as_float((unsigned)hi << 16);
      al.s[j] = (short)f2bf(f[j] - hif);
    }
    const short* bh_base = whio + ((size_t)(kt * 8) * 64 + l) * 8;
    const short* bl_base = wloo + ((size_t)(kt * 8) * 64 + l) * 8;
#pragma unroll
    for (int ct = 0; ct < 8; ++ct) {
      bf16x8 bh = *(const bf16x8*)(bh_base + (size_t)ct * 512);
      bf16x8 bl = *(const bf16x8*)(bl_base + (size_t)ct * 512);
      acc[ct] = __builtin_amdgcn_mfma_f32_16x16x32_bf16(ah.v, bh, acc[ct], 0, 0, 0);
      acc[ct] = __builtin_amdgcn_mfma_f32_16x16x32_bf16(al.v, bh, acc[ct], 0, 0, 0);
      acc[ct] = __builtin_amdgcn_mfma_f32_16x16x32_bf16(ah.v, bl, acc[ct], 0, 0, 0);
    }
  }
  __syncthreads();   // all GEMM-2 LDS reads done before overwrite
#pragma unroll
  for (int ct = 0; ct < 8; ++ct) {
    int col = ct * 16 + m;
    float bcol = bo[col];
#pragma unroll
    for (int r = 0; r < 4; ++r)
      As[w * 16 + q * 4 + r][col] = acc[ct][r] + bcol;
  }
  __syncthreads();

  // ---- pooling: per-column run-length segment-sum over this block's 64 rows ----
  if (t < H) {
    int vend = N - blk0; if (vend > 64) vend = 64;
    if (vend > 0) {
      int cur = gid[blk0];
      float s = 0.f;
      for (int i = 0; i < vend; ++i) {
        int g = gid[blk0 + i];
        if (g != cur) {
          atomicAdd(&pooled[(size_t)cur * H + t], s);
          s = 0.f; cur = g;
        }
        s += As[i][t];
      }
      atomicAdd(&pooled[(size_t)cur * H + t], s);
    }
  }
}

// ---------------- final ff ----------------
__global__ __launch_bounds__(128) void k_ff(const float* __restrict__ pooled,
                                            const float* __restrict__ Wff,
                                            const float* __restrict__ bff,
                                            float* __restrict__ out, int G) {
  int g = blockIdx.x;
  int t = threadIdx.x;
  float v = pooled[(size_t)g * H + t] * Wff[t];
#pragma unroll
  for (int off = 32; off > 0; off >>= 1) v += __shfl_down(v, off, 64);
  __shared__ float red[2];
  if ((t & 63) == 0) red[t >> 6] = v;
  __syncthreads();
  if (t == 0) out[g] = red[0] + red[1] + bff[0];
}

extern "C" void kernel_launch(void* const* d_in, const int* in_sizes, int n_in,
                              void* d_out, int out_size, void* d_ws, size_t ws_size,
                              hipStream_t stream) {
  const float* x     = (const float*)d_in[0];
  const float* W_in  = (const float*)d_in[1];
  const float* b_in  = (const float*)d_in[2];
  const float* W_g0  = (const float*)d_in[3];
  const float* b_g0  = (const float*)d_in[4];
  const float* W_g1  = (const float*)d_in[5];
  const float* b_g1  = (const float*)d_in[6];
  const float* W_g2  = (const float*)d_in[7];
  const float* b_g2  = (const float*)d_in[8];
  const float* W_out = (const float*)d_in[9];
  const float* b_out = (const float*)d_in[10];
  const float* W_ff  = (const float*)d_in[11];
  const float* b_ff  = (const float*)d_in[12];
  const int* src = (const int*)d_in[13];
  const int* dst = (const int*)d_in[14];
  const int* gid = (const int*)d_in[15];
  float* out = (float*)d_out;

  const int N = in_sizes[15];          // 50000
  const int E = in_sizes[13];          // 600000
  const int K_IN = in_sizes[1] / H;    // 74
  const int G = out_size;              // 500

  char* ws = (char*)d_ws;
  size_t off = 0;
  auto alloc = [&](size_t bytes) -> void* {
    void* p = ws + off;
    off = (off + bytes + 255) & ~(size_t)255;
    return p;
  };
  // aggregion: 25.6 MB region; first half holds bf16 gather output; whole region aliases ppack
  char*           aggregion = (char*)alloc((size_t)N * H * 4);
  unsigned*       aggb = (unsigned*)aggregion;                       // N x 64 words (bf16 pairs)
  unsigned short* hb0  = (unsigned short*)alloc((size_t)N * H * 2); // bf16 ping
  unsigned short* hb1  = (unsigned short*)alloc((size_t)N * H * 2); // bf16 pong
  float* onorm     = (float*)alloc((size_t)N * 4);
  float* inorm     = (float*)alloc((size_t)N * 4);
  int*   deg       = (int*)alloc((size_t)N * 4);
  int*   row_start = (int*)alloc((size_t)N * 4);
  int*   csr       = (int*)alloc((size_t)E * 4);
  float* pooled    = (float*)alloc((size_t)G * H * 4);
  int*   gcount    = (int*)alloc(256);

  // pre-split weight frags (hi/lo bf16, B-frag order)
  const int KT_IN = (K_IN + 31) >> 5;
  const int fr_in = KT_IN * 4096, fr_h = 4 * 4096;
  const int total_fr = fr_in + 4 * fr_h;
  short* whi_buf = (short*)alloc((size_t)total_fr * 2);
  short* wlo_buf = (short*)alloc((size_t)total_fr * 2);

  // packed hist partials alias aggregion (dead until first gather, long after CSR build):
  // nr*NCHUNK*RSIZE ints = 4*96*16384*4 = 25.17 MB <= N*H*4 = 25.6 MB.
  int nr = (N + RSIZE - 1) / RSIZE;
  int* ppack = (int*)aggregion;

  WSplitArgs wa;
  wa.W[0] = W_in;  wa.W[1] = W_g0; wa.W[2] = W_g1; wa.W[3] = W_g2; wa.W[4] = W_out;
  wa.K[0] = K_IN;  wa.K[1] = H;    wa.K[2] = H;    wa.K[3] = H;    wa.K[4] = H;
  wa.off[0] = 0;
  wa.off[1] = fr_in;
  for (int i = 2; i <= 5; ++i) wa.off[i] = wa.off[i - 1] + fr_h;
  k_wsplit<<<(total_fr + 255) / 256, 256, 0, stream>>>(wa, whi_buf, wlo_buf);

  short* whi_in = whi_buf + wa.off[0]; short* wlo_in = wlo_buf + wa.off[0];
  short* whi_g0 = whi_buf + wa.off[1]; short* wlo_g0 = wlo_buf + wa.off[1];
  short* whi_g1 = whi_buf + wa.off[2]; short* wlo_g1 = wlo_buf + wa.off[2];
  short* whi_g2 = whi_buf + wa.off[3]; short* wlo_g2 = wlo_buf + wa.off[3];
  short* whi_o  = whi_buf + wa.off[4]; short* wlo_o  = wlo_buf + wa.off[4];

  // front: zero(pooled,gcount) || embedding_in GEMM || hist — one launch
  int gblk = (N + 63) / 64;
  int GH = G * H;
  int zb = (GH + 255) / 256;
  int histblk = nr * NCHUNK;
  k_front<<<zb + gblk + histblk, 256, 0, stream>>>(src, dst, ppack, E,
                                                   x, whi_in, wlo_in, b_in, hb0,
                                                   pooled, GH, gcount, N, K_IN, zb, gblk);

  // mid: degrees/norms + chunk-prefix + block-atomic row_start
  int nb = (N + 1023) / 1024;
  k_mid<<<nb, 1024, 0, stream>>>(ppack, deg, onorm, inorm, row_start, gcount, N);

  k_fill_nr<<<histblk, 256, 0, stream>>>(src, dst, row_start, ppack, csr, N, E);

  // layer 0 (onorm applied per-edge, hb0 unscaled)
  k_gather_bf<<<N, 64, 0, stream>>>((const unsigned*)hb0, csr, row_start, deg, onorm, inorm, aggb, N);
  k_gemm_bfA<<<gblk, 256, 0, stream>>>((const unsigned short*)aggb, whi_g0, wlo_g0, b_g0,
                                       onorm, nullptr, hb1, N, 1);
  // layer 1 (onorm pre-folded in hb1)
  k_gather_bf<<<N, 64, 0, stream>>>((const unsigned*)hb1, csr, row_start, deg, nullptr, inorm, aggb, N);
  k_gemm_bfA<<<gblk, 256, 0, stream>>>((const unsigned short*)aggb, whi_g1, wlo_g1, b_g1,
                                       onorm, nullptr, hb0, N, 1);
  // layer 2 gather, then fused GEMM(g2)+silu -> GEMM(out) -> pooled
  k_gather_bf<<<N, 64, 0, stream>>>((const unsigned*)hb0, csr, row_start, deg, nullptr, inorm, aggb, N);
  k_final<<<gblk, 256, 0, stream>>>((const unsigned short*)aggb, whi_g2, wlo_g2, b_g2,
                                    whi_o, wlo_o, b_out, gid, pooled, N);

  k_ff<<<G, 128, 0, stream>>>(pooled, W_ff, b_ff, out, G);
}

// Round 18
// 311.772 us; speedup vs baseline: 1.0850x; 1.0850x over previous
//
#include <hip/hip_runtime.h>
#include <math.h>

#define H 128
#define RBITS 13
#define RSIZE 8192        // nodes per range (32 KB packed LDS histogram; 64 KB regressed: occupancy tax on merged front — R16)
#define NCHUNK 96         // edge chunks

typedef __attribute__((ext_vector_type(8))) short bf16x8;
typedef __attribute__((ext_vector_type(4))) float f32x4;

__device__ inline unsigned short f2bf(float f) {      // RNE float->bf16
  unsigned u = __float_as_uint(f);
  return (unsigned short)((u + 0x7FFF + ((u >> 16) & 1)) >> 16);
}

// ---------------- weight split: fp32 W[Kx128] -> hi/lo bf16 in B-frag order, once per launch ----------------
struct WSplitArgs {
  const float* W[5];
  int K[5];
  int off[6];     // in shorts, cumulative frag-space offsets
};
__global__ __launch_bounds__(256) void k_wsplit(WSplitArgs a, short* __restrict__ hi_buf,
                                                short* __restrict__ lo_buf) {
  int idx = blockIdx.x * 256 + threadIdx.x;
  if (idx >= a.off[5]) return;
  int wsel = 0;
  while (idx >= a.off[wsel + 1]) ++wsel;
  int lidx = idx - a.off[wsel];
  int j  = lidx & 7;
  int ln = (lidx >> 3) & 63;
  int ct = (lidx >> 9) & 7;
  int kt = lidx >> 12;
  int k = (kt << 5) | ((ln >> 4) << 3) | j;
  int n = (ct << 4) | (ln & 15);
  float v = (k < a.K[wsel]) ? a.W[wsel][(size_t)k * H + n] : 0.f;
  unsigned short hi = f2bf(v);
  float hif = __uint_as_float((unsigned)hi << 16);
  unsigned short lo = f2bf(v - hif);
  hi_buf[idx] = (short)hi;
  lo_buf[idx] = (short)lo;
}

// ---------------- split-bf16 MFMA GEMM body (A fp32 from global) ----------------
__device__ __forceinline__ void gemm_body(int blk, int tid,
                                          const float* __restrict__ A,
                                          const short* __restrict__ whi,
                                          const short* __restrict__ wlo,
                                          const float* __restrict__ bias,
                                          float* __restrict__ out_f,
                                          unsigned short* __restrict__ out_bf,
                                          int N, int K, int do_silu) {
  const int w = tid >> 6;
  const int l = tid & 63;
  const int q = l >> 4;
  const int m = l & 15;
  const int rbase = blk * 64 + w * 16;
  const int row = rbase + m;
  const bool rowOK = row < N;
  const float* Ap = A + (size_t)(rowOK ? row : 0) * K;
  const int KT = (K + 31) >> 5;

  f32x4 acc[8];
#pragma unroll
  for (int ct = 0; ct < 8; ++ct) acc[ct] = (f32x4){0.f, 0.f, 0.f, 0.f};

  for (int kt = 0; kt < KT; ++kt) {
    int kbase = kt * 32 + q * 8;
    float f[8];
    if (rowOK && kbase + 8 <= K) {
      float4 f0 = *(const float4*)(Ap + kbase);
      float4 f1 = *(const float4*)(Ap + kbase + 4);
      f[0] = f0.x; f[1] = f0.y; f[2] = f0.z; f[3] = f0.w;
      f[4] = f1.x; f[5] = f1.y; f[6] = f1.z; f[7] = f1.w;
    } else {
#pragma unroll
      for (int j = 0; j < 8; ++j)
        f[j] = (rowOK && kbase + j < K) ? Ap[kbase + j] : 0.f;
    }
    union { bf16x8 v; short s[8]; } ah, al;
#pragma unroll
    for (int j = 0; j < 8; ++j) {
      unsigned short hi = f2bf(f[j]);
      ah.s[j] = (short)hi;
      float hif = __uint_as_float((unsigned)hi << 16);
      al.s[j] = (short)f2bf(f[j] - hif);
    }
    const short* bh_base = whi + ((size_t)(kt * 8) * 64 + l) * 8;
    const short* bl_base = wlo + ((size_t)(kt * 8) * 64 + l) * 8;
#pragma unroll
    for (int ct = 0; ct < 8; ++ct) {
      bf16x8 bh = *(const bf16x8*)(bh_base + (size_t)ct * 512);
      bf16x8 bl = *(const bf16x8*)(bl_base + (size_t)ct * 512);
      acc[ct] = __builtin_amdgcn_mfma_f32_16x16x32_bf16(ah.v, bh, acc[ct], 0, 0, 0);
      acc[ct] = __builtin_amdgcn_mfma_f32_16x16x32_bf16(al.v, bh, acc[ct], 0, 0, 0);
      acc[ct] = __builtin_amdgcn_mfma_f32_16x16x32_bf16(ah.v, bl, acc[ct], 0, 0, 0);
    }
  }

  int orow[4]; bool ok[4];
#pragma unroll
  for (int r = 0; r < 4; ++r) { orow[r] = rbase + q * 4 + r; ok[r] = orow[r] < N; }
#pragma unroll
  for (int ct = 0; ct < 8; ++ct) {
    int col = ct * 16 + m;
    float bcol = bias[col];
    if (out_bf) {
#pragma unroll
      for (int r = 0; r < 4; ++r) {
        if (ok[r]) {
          float v = acc[ct][r] + bcol;
          v = v / (1.f + expf(-v));     // silu
          out_bf[(size_t)orow[r] * H + col] = f2bf(v);
        }
      }
    } else {
#pragma unroll
      for (int r = 0; r < 4; ++r) {
        if (ok[r]) {
          float v = acc[ct][r] + bcol;
          if (do_silu) v = v / (1.f + expf(-v));
          out_f[(size_t)orow[r] * H + col] = v;
        }
      }
    }
  }
}

// ---------------- bf16-A MFMA GEMM: A[N x 128] bf16 rows; acc = A*Wh + A*Wl (2-term) ----------------
__global__ __launch_bounds__(256) void k_gemm_bfA(const unsigned short* __restrict__ A,
                                                  const short* __restrict__ whi,
                                                  const short* __restrict__ wlo,
                                                  const float* __restrict__ bias,
                                                  const float* __restrict__ onorm, // fold into bf16 out
                                                  float* __restrict__ out_f,
                                                  unsigned short* __restrict__ out_bf,
                                                  int N, int do_silu) {
  const int t = threadIdx.x;
  const int w = t >> 6, l = t & 63, q = l >> 4, m = l & 15;
  const int rbase = blockIdx.x * 64 + w * 16;
  const int row = rbase + m;
  const bool rowOK = row < N;
  const short* Ap = (const short*)(A + (size_t)(rowOK ? row : 0) * H);

  f32x4 acc[8];
#pragma unroll
  for (int ct = 0; ct < 8; ++ct) acc[ct] = (f32x4){0.f, 0.f, 0.f, 0.f};

#pragma unroll
  for (int kt = 0; kt < 4; ++kt) {
    bf16x8 ah;
    if (rowOK) ah = *(const bf16x8*)(Ap + kt * 32 + q * 8);
    else       ah = (bf16x8){0,0,0,0,0,0,0,0};
    const short* bh_base = whi + ((size_t)(kt * 8) * 64 + l) * 8;
    const short* bl_base = wlo + ((size_t)(kt * 8) * 64 + l) * 8;
#pragma unroll
    for (int ct = 0; ct < 8; ++ct) {
      bf16x8 bh = *(const bf16x8*)(bh_base + (size_t)ct * 512);
      bf16x8 bl = *(const bf16x8*)(bl_base + (size_t)ct * 512);
      acc[ct] = __builtin_amdgcn_mfma_f32_16x16x32_bf16(ah, bh, acc[ct], 0, 0, 0);
      acc[ct] = __builtin_amdgcn_mfma_f32_16x16x32_bf16(ah, bl, acc[ct], 0, 0, 0);
    }
  }

  int orow[4]; bool ok[4]; float on_[4];
#pragma unroll
  for (int r = 0; r < 4; ++r) {
    orow[r] = rbase + q * 4 + r;
    ok[r] = orow[r] < N;
    on_[r] = (out_bf && onorm && ok[r]) ? onorm[orow[r]] : 1.f;
  }
#pragma unroll
  for (int ct = 0; ct < 8; ++ct) {
    int col = ct * 16 + m;
    float bcol = bias[col];
    if (out_bf) {
#pragma unroll
      for (int r = 0; r < 4; ++r) {
        if (ok[r]) {
          float v = acc[ct][r] + bcol;
          v = v / (1.f + expf(-v));     // silu
          out_bf[(size_t)orow[r] * H + col] = f2bf(v * on_[r]);
        }
      }
    } else {
#pragma unroll
      for (int r = 0; r < 4; ++r) {
        if (ok[r]) {
          float v = acc[ct][r] + bcol;
          if (do_silu) v = v / (1.f + expf(-v));
          out_f[(size_t)orow[r] * H + col] = v;
        }
      }
    }
  }
}

// ---------------- front: [zero pooled+gcount] || [embedding_in GEMM] || [hist] in ONE launch ----------------
__global__ __launch_bounds__(256) void k_front(const int* __restrict__ src,
                                               const int* __restrict__ dst,
                                               int* __restrict__ ppack, int E,
                                               const float* __restrict__ x,
                                               const short* __restrict__ whi_in,
                                               const short* __restrict__ wlo_in,
                                               const float* __restrict__ b_in,
                                               unsigned short* __restrict__ hb0,
                                               float* __restrict__ pooled, int GH,
                                               int* __restrict__ gcount,
                                               int N, int K_IN, int zb, int gblk) {
  __shared__ int h[RSIZE];
  int b = blockIdx.x;
  int t = threadIdx.x;
  if (b < zb) {
    int idx = b * 256 + t;
    if (idx < GH) pooled[idx] = 0.f;
    if (b == 0 && t == 0) *gcount = 0;
    return;
  }
  b -= zb;
  if (b < gblk) {
    // embedding_in: hb0 = bf16(silu(x @ W_in + b_in))  (onorm applied in gather-0)
    gemm_body(b, t, x, whi_in, wlo_in, b_in, nullptr, hb0, N, K_IN, 1);
    return;
  }
  b -= gblk;
  int r = b / NCHUNK, c = b % NCHUNK;
  int base = r << RBITS;
  for (int i = t; i < RSIZE; i += 256) h[i] = 0;
  __syncthreads();
  int e0 = (int)(((long long)E * c) / NCHUNK);
  int e1 = (int)(((long long)E * (c + 1)) / NCHUNK);
  for (int e = e0 + t; e < e1; e += 256) {
    unsigned ls = (unsigned)(src[e] - base);
    if (ls < RSIZE) atomicAdd(&h[ls], 1);
    unsigned ld = (unsigned)(dst[e] - base);
    if (ld < RSIZE) atomicAdd(&h[ld], 0x10000);
  }
  __syncthreads();
  int* p = ppack + (((size_t)(r * NCHUNK + c)) << RBITS);
  for (int i = t; i < RSIZE; i += 256) p[i] = h[i];
}

// ---------------- mid: degrees/norms + ppack chunk-prefix + block-atomic row_start ----------------
__global__ __launch_bounds__(1024) void k_mid(int* __restrict__ ppack,
                                              int* __restrict__ deg,
                                              float* __restrict__ onorm,
                                              float* __restrict__ inorm,
                                              int* __restrict__ row_start,
                                              int* __restrict__ gcount, int N) {
  __shared__ int buf[1024];
  __shared__ int base_s;
  int i = blockIdx.x * 1024 + threadIdx.x;
  int run = 0;
  if (i < N) {
    int r = i >> RBITS, l = i & (RSIZE - 1);
    size_t rb = ((size_t)r * NCHUNK) << RBITS;
    int sumS = 0;
    for (int c = 0; c < NCHUNK; ++c) {
      size_t idx = rb + ((size_t)c << RBITS) + l;
      int v = ppack[idx];
      sumS += v & 0xFFFF;
      ppack[idx] = run;
      run += (v >> 16) & 0xFFFF;
    }
    deg[i] = run;
    int od = sumS < 1 ? 1 : sumS;
    int id = run < 1 ? 1 : run;
    onorm[i] = rsqrtf((float)od);
    inorm[i] = rsqrtf((float)id);
  }
  buf[threadIdx.x] = run;
  __syncthreads();
#pragma unroll
  for (int off = 1; off < 1024; off <<= 1) {
    int tv = 0;
    if (threadIdx.x >= off) tv = buf[threadIdx.x - off];
    __syncthreads();
    if (threadIdx.x >= off) buf[threadIdx.x] += tv;
    __syncthreads();
  }
  if (threadIdx.x == 1023) base_s = atomicAdd(gcount, buf[1023]);
  __syncthreads();
  if (i < N) row_start[i] = base_s + buf[threadIdx.x] - run;
}

// ---------------- CSR fill: LDS cursors seeded from row_start + chunk prefix ----------------
__global__ __launch_bounds__(256) void k_fill_nr(const int* __restrict__ src,
                                                 const int* __restrict__ dst,
                                                 const int* __restrict__ row_start,
                                                 const int* __restrict__ ppfx,
                                                 int* __restrict__ csr, int N, int E) {
  int r = blockIdx.x / NCHUNK, c = blockIdx.x % NCHUNK;
  int base = r << RBITS;
  __shared__ int cur[RSIZE];
  const int* pd = ppfx + (((size_t)(r * NCHUNK + c)) << RBITS);
  for (int i = threadIdx.x; i < RSIZE; i += 256) {
    int node = base + i;
    cur[i] = (node < N) ? (row_start[node] + pd[i]) : 0;
  }
  __syncthreads();
  int e0 = (int)(((long long)E * c) / NCHUNK);
  int e1 = (int)(((long long)E * (c + 1)) / NCHUNK);
  for (int e = e0 + threadIdx.x; e < e1; e += 256) {
    unsigned ld = (unsigned)(dst[e] - base);
    if (ld < RSIZE) {
      int pos = atomicAdd(&cur[ld], 1);   // LDS atomic
      csr[pos] = src[e];
    }
  }
}

// ---------------- gather: edge-paired + unroll x2, 4 edges/iter, 2 loads in flight ----------------
__global__ __launch_bounds__(64) void k_gather_bf(const unsigned* __restrict__ hb, // N x 64 words
                                                  const int* __restrict__ csr_src,
                                                  const int* __restrict__ row_start,
                                                  const int* __restrict__ deg,
                                                  const float* __restrict__ onorm, // null if pre-folded
                                                  const float* __restrict__ inorm,
                                                  unsigned* __restrict__ aggb, int N) {
  int v = blockIdx.x;
  int t = threadIdx.x;
  int half = t >> 5, u = t & 31;
  int b = row_start[v], e = b + deg[v];
  float a0 = 0.f, a1 = 0.f, a2 = 0.f, a3 = 0.f;
  int i = b;
  if (onorm) {
    for (; i + 4 <= e; i += 4) {          // two independent pairs -> 2 loads in flight
      int s0 = csr_src[i + half];
      int s1 = csr_src[i + 2 + half];
      float on0 = onorm[s0], on1 = onorm[s1];
      uint2 p0 = *(const uint2*)(hb + (size_t)s0 * 64 + 2 * u);
      uint2 p1 = *(const uint2*)(hb + (size_t)s1 * 64 + 2 * u);
      a0 += __uint_as_float(p0.x << 16) * on0;
      a1 += __uint_as_float(p0.x & 0xFFFF0000u) * on0;
      a2 += __uint_as_float(p0.y << 16) * on0;
      a3 += __uint_as_float(p0.y & 0xFFFF0000u) * on0;
      a0 += __uint_as_float(p1.x << 16) * on1;
      a1 += __uint_as_float(p1.x & 0xFFFF0000u) * on1;
      a2 += __uint_as_float(p1.y << 16) * on1;
      a3 += __uint_as_float(p1.y & 0xFFFF0000u) * on1;
    }
    for (; i + 2 <= e; i += 2) {
      int s = csr_src[i + half];
      float on = onorm[s];
      uint2 p = *(const uint2*)(hb + (size_t)s * 64 + 2 * u);
      a0 += __uint_as_float(p.x << 16) * on;
      a1 += __uint_as_float(p.x & 0xFFFF0000u) * on;
      a2 += __uint_as_float(p.y << 16) * on;
      a3 += __uint_as_float(p.y & 0xFFFF0000u) * on;
    }
    if (i < e && half == 0) {
      int s = csr_src[i];
      float on = onorm[s];
      uint2 p = *(const uint2*)(hb + (size_t)s * 64 + 2 * u);
      a0 += __uint_as_float(p.x << 16) * on;
      a1 += __uint_as_float(p.x & 0xFFFF0000u) * on;
      a2 += __uint_as_float(p.y << 16) * on;
      a3 += __uint_as_float(p.y & 0xFFFF0000u) * on;
    }
  } else {
    for (; i + 4 <= e; i += 4) {
      int s0 = csr_src[i + half];
      int s1 = csr_src[i + 2 + half];
      uint2 p0 = *(const uint2*)(hb + (size_t)s0 * 64 + 2 * u);
      uint2 p1 = *(const uint2*)(hb + (size_t)s1 * 64 + 2 * u);
      a0 += __uint_as_float(p0.x << 16);
      a1 += __uint_as_float(p0.x & 0xFFFF0000u);
      a2 += __uint_as_float(p0.y << 16);
      a3 += __uint_as_float(p0.y & 0xFFFF0000u);
      a0 += __uint_as_float(p1.x << 16);
      a1 += __uint_as_float(p1.x & 0xFFFF0000u);
      a2 += __uint_as_float(p1.y << 16);
      a3 += __uint_as_float(p1.y & 0xFFFF0000u);
    }
    for (; i + 2 <= e; i += 2) {
      int s = csr_src[i + half];
      uint2 p = *(const uint2*)(hb + (size_t)s * 64 + 2 * u);
      a0 += __uint_as_float(p.x << 16);
      a1 += __uint_as_float(p.x & 0xFFFF0000u);
      a2 += __uint_as_float(p.y << 16);
      a3 += __uint_as_float(p.y & 0xFFFF0000u);
    }
    if (i < e && half == 0) {
      int s = csr_src[i];
      uint2 p = *(const uint2*)(hb + (size_t)s * 64 + 2 * u);
      a0 += __uint_as_float(p.x << 16);
      a1 += __uint_as_float(p.x & 0xFFFF0000u);
      a2 += __uint_as_float(p.y << 16);
      a3 += __uint_as_float(p.y & 0xFFFF0000u);
    }
  }
  // combine halves (xor-32 swap) — adds even-edge and odd-edge partial sums
  a0 += __shfl_xor(a0, 32, 64);
  a1 += __shfl_xor(a1, 32, 64);
  a2 += __shfl_xor(a2, 32, 64);
  a3 += __shfl_xor(a3, 32, 64);
  if (half == 0) {
    float inn = inorm[v];
    uint2 o;
    o.x = (unsigned)f2bf(a0 * inn) | ((unsigned)f2bf(a1 * inn) << 16);
    o.y = (unsigned)f2bf(a2 * inn) | ((unsigned)f2bf(a3 * inn) << 16);
    *(uint2*)(aggb + (size_t)v * 64 + 2 * u) = o;
  }
}

// ---------------- fused tail: h3 = silu(Abf@Wg2+b2); hf = h3@Wout+bo; pooled += segsum(hf) ----------------
__global__ __launch_bounds__(256) void k_final(const unsigned short* __restrict__ A, // bf16 rows
                                               const short* __restrict__ whi2,
                                               const short* __restrict__ wlo2,
                                               const float* __restrict__ b2,
                                               const short* __restrict__ whio,
                                               const short* __restrict__ wloo,
                                               const float* __restrict__ bo,
                                               const int* __restrict__ gid,
                                               float* __restrict__ pooled, int N) {
  __shared__ float As[64][132];
  const int t = threadIdx.x;
  const int w = t >> 6, l = t & 63, q = l >> 4, m = l & 15;
  const int blk0 = blockIdx.x * 64;
  const int rbase = blk0 + w * 16;
  const int row = rbase + m;
  const bool rowOK = row < N;
  const short* Ap = (const short*)(A + (size_t)(rowOK ? row : 0) * H);

  f32x4 acc[8];
#pragma unroll
  for (int ct = 0; ct < 8; ++ct) acc[ct] = (f32x4){0.f, 0.f, 0.f, 0.f};

  // ---- GEMM 1: silu(Abf @ Wg2 + b2), 2-term ----
#pragma unroll
  for (int kt = 0; kt < 4; ++kt) {
    bf16x8 ah;
    if (rowOK) ah = *(const bf16x8*)(Ap + kt * 32 + q * 8);
    else       ah = (bf16x8){0,0,0,0,0,0,0,0};
    const short* bh_base = whi2 + ((size_t)(kt * 8) * 64 + l) * 8;
    const short* bl_base = wlo2 + ((size_t)(kt * 8) * 64 + l) * 8;
#pragma unroll
    for (int ct = 0; ct < 8; ++ct) {
      bf16x8 bh = *(const bf16x8*)(bh_base + (size_t)ct * 512);
      bf16x8 bl = *(const bf16x8*)(bl_base + (size_t)ct * 512);
      acc[ct] = __builtin_amdgcn_mfma_f32_16x16x32_bf16(ah, bh, acc[ct], 0, 0, 0);
      acc[ct] = __builtin_amdgcn_mfma_f32_16x16x32_bf16(ah, bl, acc[ct], 0, 0, 0);
    }
  }
#pragma unroll
  for (int ct = 0; ct < 8; ++ct) {
    int col = ct * 16 + m;
    float bcol = b2[col];
#pragma unroll
    for (int r = 0; r < 4; ++r) {
      float v = acc[ct][r] + bcol;
      v = v / (1.f + expf(-v));         // silu
      As[w * 16 + q * 4 + r][col] = v;
    }
  }
  __syncthreads();

  // ---- GEMM 2: (h3 fp32 from LDS) @ Wout + bo, 3-term ----
#pragma unroll
  for (int ct = 0; ct < 8; ++ct) acc[ct] = (f32x4){0.f, 0.f, 0.f, 0.f};
#pragma unroll
  for (int kt = 0; kt < 4; ++kt) {
    int kbase = kt * 32 + q * 8;
    float f[8];
    *(float4*)&f[0] = *(const float4*)(&As[w * 16 + m][kbase]);
    *(float4*)&f[4] = *(const float4*)(&As[w * 16 + m][kbase + 4]);
    union { bf16x8 v; short s[8]; } ah, al;
#pragma unroll
    for (int j = 0; j < 8; ++j) {
      unsigned short hi = f2bf(f[j]);
      ah.s[j] = (short)hi;
      float hif = __uint_as_float((unsigned)hi << 16);
      al.s[j] = (short)f2bf(f[j] - hif);
    }
    const short* bh_base = whio + ((size_t)(kt * 8) * 64 + l) * 8;
    const short* bl_base = wloo + ((size_t)(kt * 8) * 64 + l) * 8;
#pragma unroll
    for (int ct = 0; ct < 8; ++ct) {
      bf16x8 bh = *(const bf16x8*)(bh_base + (size_t)ct * 512);
      bf16x8 bl = *(const bf16x8*)(bl_base + (size_t)ct * 512);
      acc[ct] = __builtin_amdgcn_mfma_f32_16x16x32_bf16(ah.v, bh, acc[ct], 0, 0, 0);
      acc[ct] = __builtin_amdgcn_mfma_f32_16x16x32_bf16(al.v, bh, acc[ct], 0, 0, 0);
      acc[ct] = __builtin_amdgcn_mfma_f32_16x16x32_bf16(ah.v, bl, acc[ct], 0, 0, 0);
    }
  }
  __syncthreads();   // all GEMM-2 LDS reads done before overwrite
#pragma unroll
  for (int ct = 0; ct < 8; ++ct) {
    int col = ct * 16 + m;
    float bcol = bo[col];
#pragma unroll
    for (int r = 0; r < 4; ++r)
      As[w * 16 + q * 4 + r][col] = acc[ct][r] + bcol;
  }
  __syncthreads();

  // ---- pooling: per-column run-length segment-sum over this block's 64 rows ----
  if (t < H) {
    int vend = N - blk0; if (vend > 64) vend = 64;
    if (vend > 0) {
      int cur = gid[blk0];
      float s = 0.f;
      for (int i = 0; i < vend; ++i) {
        int g = gid[blk0 + i];
        if (g != cur) {
          atomicAdd(&pooled[(size_t)cur * H + t], s);
          s = 0.f; cur = g;
        }
        s += As[i][t];
      }
      atomicAdd(&pooled[(size_t)cur * H + t], s);
    }
  }
}

// ---------------- final ff ----------------
__global__ __launch_bounds__(128) void k_ff(const float* __restrict__ pooled,
                                            const float* __restrict__ Wff,
                                            const float* __restrict__ bff,
                                            float* __restrict__ out, int G) {
  int g = blockIdx.x;
  int t = threadIdx.x;
  float v = pooled[(size_t)g * H + t] * Wff[t];
#pragma unroll
  for (int off = 32; off > 0; off >>= 1) v += __shfl_down(v, off, 64);
  __shared__ float red[2];
  if ((t & 63) == 0) red[t >> 6] = v;
  __syncthreads();
  if (t == 0) out[g] = red[0] + red[1] + bff[0];
}

extern "C" void kernel_launch(void* const* d_in, const int* in_sizes, int n_in,
                              void* d_out, int out_size, void* d_ws, size_t ws_size,
                              hipStream_t stream) {
  const float* x     = (const float*)d_in[0];
  const float* W_in  = (const float*)d_in[1];
  const float* b_in  = (const float*)d_in[2];
  const float* W_g0  = (const float*)d_in[3];
  const float* b_g0  = (const float*)d_in[4];
  const float* W_g1  = (const float*)d_in[5];
  const float* b_g1  = (const float*)d_in[6];
  const float* W_g2  = (const float*)d_in[7];
  const float* b_g2  = (const float*)d_in[8];
  const float* W_out = (const float*)d_in[9];
  const float* b_out = (const float*)d_in[10];
  const float* W_ff  = (const float*)d_in[11];
  const float* b_ff  = (const float*)d_in[12];
  const int* src = (const int*)d_in[13];
  const int* dst = (const int*)d_in[14];
  const int* gid = (const int*)d_in[15];
  float* out = (float*)d_out;

  const int N = in_sizes[15];          // 50000
  const int E = in_sizes[13];          // 600000
  const int K_IN = in_sizes[1] / H;    // 74
  const int G = out_size;              // 500

  char* ws = (char*)d_ws;
  size_t off = 0;
  auto alloc = [&](size_t bytes) -> void* {
    void* p = ws + off;
    off = (off + bytes + 255) & ~(size_t)255;
    return p;
  };
  // aggregion: 25.6 MB region; first half holds bf16 gather output; whole region aliases ppack
  char*           aggregion = (char*)alloc((size_t)N * H * 4);
  unsigned*       aggb = (unsigned*)aggregion;                       // N x 64 words (bf16 pairs)
  unsigned short* hb0  = (unsigned short*)alloc((size_t)N * H * 2); // bf16 ping
  unsigned short* hb1  = (unsigned short*)alloc((size_t)N * H * 2); // bf16 pong
  float* onorm     = (float*)alloc((size_t)N * 4);
  float* inorm     = (float*)alloc((size_t)N * 4);
  int*   deg       = (int*)alloc((size_t)N * 4);
  int*   row_start = (int*)alloc((size_t)N * 4);
  int*   csr       = (int*)alloc((size_t)E * 4);
  float* pooled    = (float*)alloc((size_t)G * H * 4);
  int*   gcount    = (int*)alloc(256);

  // pre-split weight frags (hi/lo bf16, B-frag order)
  const int KT_IN = (K_IN + 31) >> 5;
  const int fr_in = KT_IN * 4096, fr_h = 4 * 4096;
  const int total_fr = fr_in + 4 * fr_h;
  short* whi_buf = (short*)alloc((size_t)total_fr * 2);
  short* wlo_buf = (short*)alloc((size_t)total_fr * 2);

  // packed hist partials alias aggregion (dead until first gather, long after CSR build):
  // nr*NCHUNK*RSIZE ints = 7*96*8192*4 = 22.0 MB <= 25.6 MB.
  int nr = (N + RSIZE - 1) / RSIZE;
  int* ppack = (int*)aggregion;

  WSplitArgs wa;
  wa.W[0] = W_in;  wa.W[1] = W_g0; wa.W[2] = W_g1; wa.W[3] = W_g2; wa.W[4] = W_out;
  wa.K[0] = K_IN;  wa.K[1] = H;    wa.K[2] = H;    wa.K[3] = H;    wa.K[4] = H;
  wa.off[0] = 0;
  wa.off[1] = fr_in;
  for (int i = 2; i <= 5; ++i) wa.off[i] = wa.off[i - 1] + fr_h;
  k_wsplit<<<(total_fr + 255) / 256, 256, 0, stream>>>(wa, whi_buf, wlo_buf);

  short* whi_in = whi_buf + wa.off[0]; short* wlo_in = wlo_buf + wa.off[0];
  short* whi_g0 = whi_buf + wa.off[1]; short* wlo_g0 = wlo_buf + wa.off[1];
  short* whi_g1 = whi_buf + wa.off[2]; short* wlo_g1 = wlo_buf + wa.off[2];
  short* whi_g2 = whi_buf + wa.off[3]; short* wlo_g2 = wlo_buf + wa.off[3];
  short* whi_o  = whi_buf + wa.off[4]; short* wlo_o  = wlo_buf + wa.off[4];

  // front: zero(pooled,gcount) || embedding_in GEMM || hist — one launch
  int gblk = (N + 63) / 64;
  int GH = G * H;
  int zb = (GH + 255) / 256;
  int histblk = nr * NCHUNK;
  k_front<<<zb + gblk + histblk, 256, 0, stream>>>(src, dst, ppack, E,
                                                   x, whi_in, wlo_in, b_in, hb0,
                                                   pooled, GH, gcount, N, K_IN, zb, gblk);

  // mid: degrees/norms + chunk-prefix + block-atomic row_start
  int nb = (N + 1023) / 1024;
  k_mid<<<nb, 1024, 0, stream>>>(ppack, deg, onorm, inorm, row_start, gcount, N);

  k_fill_nr<<<histblk, 256, 0, stream>>>(src, dst, row_start, ppack, csr, N, E);

  // layer 0 (onorm applied per-edge, hb0 unscaled)
  k_gather_bf<<<N, 64, 0, stream>>>((const unsigned*)hb0, csr, row_start, deg, onorm, inorm, aggb, N);
  k_gemm_bfA<<<gblk, 256, 0, stream>>>((const unsigned short*)aggb, whi_g0, wlo_g0, b_g0,
                                       onorm, nullptr, hb1, N, 1);
  // layer 1 (onorm pre-folded in hb1)
  k_gather_bf<<<N, 64, 0, stream>>>((const unsigned*)hb1, csr, row_start, deg, nullptr, inorm, aggb, N);
  k_gemm_bfA<<<gblk, 256, 0, stream>>>((const unsigned short*)aggb, whi_g1, wlo_g1, b_g1,
                                       onorm, nullptr, hb0, N, 1);
  // layer 2 gather, then fused GEMM(g2)+silu -> GEMM(out) -> pooled
  k_gather_bf<<<N, 64, 0, stream>>>((const unsigned*)hb0, csr, row_start, deg, nullptr, inorm, aggb, N);
  k_final<<<gblk, 256, 0, stream>>>((const unsigned short*)aggb, whi_g2, wlo_g2, b_g2,
                                    whi_o, wlo_o, b_out, gid, pooled, N);

  k_ff<<<G, 128, 0, stream>>>(pooled, W_ff, b_ff, out, G);
}